// Round 1
// 234.917 us; speedup vs baseline: 1.0754x; 1.0754x over previous
//
#include <hip/hip_runtime.h>

// GatedDeltaNet fused kernel for MI355X (gfx950) — R6.
// R5 + VALU-issue reduction: (1) sigmoid/tanh/l2norm use raw v_rcp_f32 /
// v_rsq_f32 (no -ffast-math in harness -> '/' was lowering to the ~9-inst
// IEEE div sequence, ~24x/thread); (2) sum16 via DPP row_ror adds (full-rate
// VALU) instead of __shfl_xor (ds_bpermute + addr math, serialized DS
// latency); (3) one-pass mean/var (E[x^2]-mean^2) so both reduction chains
// overlap; (4) compile-time tile divide.  Structure/layout unchanged.

#define TBS 32
#define ROWS 34          // TBS + 2 halo
#define DD 64
#define T_LEN 4096
#define TILES_PB 128     // T_LEN / TBS
#define LSTRIDE 72       // ushort stride: 144 B = 16B-aligned, 2-way bank alias (free)

typedef unsigned short ushort_t;
typedef short bf16x8 __attribute__((ext_vector_type(8)));
typedef float f32x4 __attribute__((ext_vector_type(4)));
typedef float f32x16 __attribute__((ext_vector_type(16)));

__device__ inline float lo2f(unsigned u) { return __uint_as_float(u << 16); }
__device__ inline float hi2f(unsigned u) { return __uint_as_float(u & 0xffff0000u); }
__device__ inline unsigned pk2(float a, float b) {    // bf16(a) in lo16, bf16(b) in hi16, RNE
    unsigned r;
    asm("v_cvt_pk_bf16_f32 %0, %1, %2" : "=v"(r) : "v"(a), "v"(b));
    return r;
}
__device__ inline ushort_t f2b(float f) {             // scalar RNE (cvt_kernel only)
    unsigned u = __float_as_uint(f);
    u += 0x7fffu + ((u >> 16) & 1u);
    return (ushort_t)(u >> 16);
}

// HW approx (~1 ulp) — avoids IEEE div/rsqrt expansions (no -ffast-math here).
__device__ inline float rcp_(float x) {
#if __has_builtin(__builtin_amdgcn_rcpf)
    return __builtin_amdgcn_rcpf(x);
#else
    float r; asm("v_rcp_f32 %0, %1" : "=v"(r) : "v"(x)); return r;
#endif
}
__device__ inline float rsq_(float x) {
#if __has_builtin(__builtin_amdgcn_rsqf)
    return __builtin_amdgcn_rsqf(x);
#else
    float r; asm("v_rsq_f32 %0, %1" : "=v"(r) : "v"(x)); return r;
#endif
}

// 16-lane sum broadcast via DPP row_ror (full-rate VALU, no DS pipe).
// Reduce groups are 16 consecutive lanes == one DPP row, all lanes active.
template<int CTRL>
__device__ inline float dpp_add(float v) {
    int t = __builtin_amdgcn_mov_dpp(__float_as_int(v), CTRL, 0xf, 0xf, true);
    return v + __int_as_float(t);
}
__device__ inline float sum16(float v) {
    v = dpp_add<0x128>(v);   // row_ror:8
    v = dpp_add<0x124>(v);   // row_ror:4
    v = dpp_add<0x122>(v);   // row_ror:2
    v = dpp_add<0x121>(v);   // row_ror:1
    return v;
}

__device__ inline float sigmoidf_(float x) { return rcp_(1.f + __expf(-x)); }
__device__ inline float tanhf_(float x) {
    float xc = fminf(fmaxf(x, -15.f), 15.f);
    float e2 = __expf(2.f * xc);
    return (e2 - 1.f) * rcp_(e2 + 1.f);
}

// ---- pre-pass: fp32 -> bf16 pack of the six 64x64 weight matrices ----------
// ushort layout: qw 0, kw 4096, vw 8192, aw 12288, bw 16384, pw 20480
__global__ __launch_bounds__(256) void cvt_kernel(
    const float* __restrict__ w0, const float* __restrict__ w1,
    const float* __restrict__ w2, const float* __restrict__ w3,
    const float* __restrict__ w4, const float* __restrict__ w5,
    ushort_t* __restrict__ dst) {
    int i = blockIdx.x * 256 + threadIdx.x;            // < 24576
    const float* ws_[6] = {w0, w1, w2, w3, w4, w5};
    dst[i] = f2b(ws_[i >> 12][i & 4095]);
}

// One 32x32 GEMM strip: D[o][t] = sum_k W[o][k]*act[t][k] + bias[o]
// o in [strip*32, strip*32+32), t in [m0, m0+32).
// A-frag (W): m=lane&31 -> o, k=(lane>>5)*8+j.  B-frag (act): n=lane&31 -> t.
// C/D: col(lane&31)=t, row=(reg&3)+8*(reg>>2)+4*(lane>>5) -> o.
__device__ inline void mm32(const ushort_t* __restrict__ W,
                            const float* __restrict__ bias,
                            const ushort_t* src, ushort_t* dst,
                            int m0, int strip, int lane) {
    const int l31  = lane & 31;
    const int half = lane >> 5;
    const int t    = m0 + l31;
    const ushort_t* wrow = W + (strip * 32 + l31) * 64 + half * 8;
    const ushort_t* arow = src + t * LSTRIDE + half * 8;
    f32x16 acc = {};
#pragma unroll
    for (int kk = 0; kk < 4; kk++) {
        bf16x8 af = *(const bf16x8*)(wrow + kk * 16);
        bf16x8 bf = *(const bf16x8*)(arow + kk * 16);
        acc = __builtin_amdgcn_mfma_f32_32x32x16_bf16(af, bf, acc, 0, 0, 0);
    }
#pragma unroll
    for (int rg = 0; rg < 4; rg++) {
        const int o0 = strip * 32 + rg * 8 + half * 4;
        f32x4 bv = *(const f32x4*)(bias + o0);
        uint2 w;
        w.x = pk2(acc[rg * 4 + 0] + bv[0], acc[rg * 4 + 1] + bv[1]);
        w.y = pk2(acc[rg * 4 + 2] + bv[2], acc[rg * 4 + 3] + bv[3]);
        *(uint2*)(dst + t * LSTRIDE + o0) = w;
    }
}

// conv3 (zero-pad) + sigmoid on 4 channels of row rr from bf16 buffer F.
__device__ inline void conv_sig4(const float* __restrict__ CW,
                                 const float* __restrict__ CB, int cb,
                                 const ushort_t* F, int rr, bool zl, bool zr,
                                 float out[4]) {
    uint2 m_ = *(const uint2*)(F + (rr - 1) * LSTRIDE + cb);
    uint2 c_ = *(const uint2*)(F + rr * LSTRIDE + cb);
    uint2 p_ = *(const uint2*)(F + (rr + 1) * LSTRIDE + cb);
    f32x4 w0 = *(const f32x4*)(CW + cb);
    f32x4 w1 = *(const f32x4*)(CW + 64 + cb);
    f32x4 w2 = *(const f32x4*)(CW + 128 + cb);
    f32x4 bb = *(const f32x4*)(CB + cb);
    float xm[4] = {lo2f(m_.x), hi2f(m_.x), lo2f(m_.y), hi2f(m_.y)};
    float x0[4] = {lo2f(c_.x), hi2f(c_.x), lo2f(c_.y), hi2f(c_.y)};
    float xp[4] = {lo2f(p_.x), hi2f(p_.x), lo2f(p_.y), hi2f(p_.y)};
#pragma unroll
    for (int i = 0; i < 4; i++) {
        float a = fmaf(w0[i], zl ? 0.f : xm[i],
                  fmaf(w1[i], x0[i],
                  fmaf(w2[i], zr ? 0.f : xp[i], bb[i])));
        out[i] = sigmoidf_(a);
    }
}

__global__ __launch_bounds__(512, 8) void gdn_kernel(
    const float* __restrict__ xg, const float* __restrict__ norm_g,
    const ushort_t* __restrict__ wpack,
    const float* __restrict__ qcw, const float* __restrict__ qcb,
    const float* __restrict__ kcw, const float* __restrict__ kcb,
    const float* __restrict__ vcw, const float* __restrict__ vcb,
    const float* __restrict__ qbf, const float* __restrict__ kbf,
    const float* __restrict__ vbf, const float* __restrict__ abf,
    const float* __restrict__ bbf, const float* __restrict__ pbf,
    const float* __restrict__ post_g,
    float* __restrict__ outg, int tiles_per_b) {
    __shared__ __align__(16) ushort_t Xs[ROWS * LSTRIDE];   // bf16 x rows t0-1..t0+32
    __shared__ __align__(16) ushort_t Hs[ROWS * LSTRIDE];   // h; rows 1..32 become Ns
    __shared__ __align__(16) ushort_t Fq[ROWS * LSTRIDE];   // qlin; later dhat
    __shared__ __align__(16) ushort_t Fk[ROWS * LSTRIDE];
    __shared__ __align__(16) ushort_t Fv[ROWS * LSTRIDE];
    __shared__ __align__(16) ushort_t Fa[ROWS * LSTRIDE];
    __shared__ __align__(16) ushort_t Fb[ROWS * LSTRIDE];
    __shared__ __align__(16) float CWs[768];
    // CWs: [0..191] q taps (tap-major [3][64]); [192..383] k; [384..575] v;
    //      [576] qcb; [640] kcb; [704] vcb

    const int tid    = threadIdx.x;
    const int wave   = tid >> 6;
    const int lane   = tid & 63;
    const int cb     = (tid & 15) * 4;   // channel base (4 ch/lane)
    const int rgrp   = tid >> 4;         // 0..31
    const int bidx = blockIdx.x;
    const int b    = bidx >> 7;          // / TILES_PB (=128, compile-time)
    const int tile = bidx & (TILES_PB - 1);
    const int t0   = tile * TBS;
    const bool left_edge  = (t0 == 0);
    const bool right_edge = (t0 + TBS >= T_LEN);

    // ---- Stage A: x from global; zc_rmsnorm in-register; Xs+Hs bf16 --------
    // One-pass: var = E[x^2] - mean^2 -> the two sum16 chains are independent.
    {
        const f32x4 gv = *(const f32x4*)(norm_g + cb);
        for (int r = rgrp; r < ROWS; r += 32) {
            int t = t0 + r - 1;
            f32x4 xv = {0.f, 0.f, 0.f, 0.f};
            if (t >= 0 && t < T_LEN)
                xv = *(const f32x4*)(xg + ((size_t)b * T_LEN + t) * DD + cb);
            float s  = (xv[0] + xv[1]) + (xv[2] + xv[3]);
            float s2 = 0.f;
#pragma unroll
            for (int i = 0; i < 4; i++) s2 = fmaf(xv[i], xv[i], s2);
            s = sum16(s); s2 = sum16(s2);
            float mean = s * (1.f / 64.f);
            float var  = fmaxf(fmaf(-mean, mean, s2 * (1.f / 64.f)), 0.f);
            float inv  = rsq_(var + 1e-8f);
            uint2 xpk; xpk.x = pk2(xv[0], xv[1]); xpk.y = pk2(xv[2], xv[3]);
            *(uint2*)(Xs + r * LSTRIDE + cb) = xpk;
            uint2 hpk;
            hpk.x = pk2((xv[0] - mean) * inv * gv[0], (xv[1] - mean) * inv * gv[1]);
            hpk.y = pk2((xv[2] - mean) * inv * gv[2], (xv[3] - mean) * inv * gv[3]);
            *(uint2*)(Hs + r * LSTRIDE + cb) = hpk;
        }
    }
    // conv taps + biases -> CWs (tap-major)
    if (tid < 192) {
        int tap = tid >> 6, c = tid & 63;
        CWs[tid]       = qcw[c * 3 + tap];
        CWs[192 + tid] = kcw[c * 3 + tap];
        CWs[384 + tid] = vcw[c * 3 + tap];
    } else if (tid < 256) {
        int c = tid - 192;
        CWs[576 + c] = qcb[c];
        CWs[640 + c] = kcb[c];
        CWs[704 + c] = vcb[c];
    }
    __syncthreads();

    // ---- Stage B: six GEMMs as 16 strip-units, 2 per wave ------------------
    // u<12: g=u>>2 (q,k,v), m-half=(u>>1)&1 -> m0 {0,2}, strip=u&1, src=Hs
    // u>=12: g'=(u-12)>>1 (a,b), m0=1, strip=u&1, src=Xs
    // Overlapping m-halves write identical values (benign).
#pragma unroll
    for (int i = 0; i < 2; i++) {
        const int u = wave * 2 + i;
        const ushort_t* W; const float* bias; const ushort_t* src; ushort_t* dst;
        int m0, strip;
        if (u < 12) {
            const int g = u >> 2, sub = u & 3;
            W = wpack + g * 4096;
            bias = (g == 0) ? qbf : (g == 1) ? kbf : vbf;
            dst  = (g == 0) ? Fq  : (g == 1) ? Fk  : Fv;
            src = Hs;
            m0 = (sub & 2) ? 2 : 0;
            strip = sub & 1;
        } else {
            const int g = (u - 12) >> 1;
            W = wpack + (3 + g) * 4096;
            bias = g ? bbf : abf;
            dst  = g ? Fb  : Fa;
            src = Xs;
            m0 = 1;
            strip = u & 1;
        }
        mm32(W, bias, src, dst, m0, strip, lane);
    }
    __syncthreads();

    // ---- Stage C: conv+sig (q,k,v), l2norm(q,k), delta, gate, post-norm ----
    {
        const int rr = rgrp + 1;                // 1..32
        const bool zl = (rr == 1) && left_edge;
        const bool zr = (rr == TBS) && right_edge;
        float qs[4], ks[4], vs[4];
        conv_sig4(CWs,       CWs + 576, cb, Fq, rr, zl, zr, qs);
        conv_sig4(CWs + 192, CWs + 640, cb, Fk, rr, zl, zr, ks);
        conv_sig4(CWs + 384, CWs + 704, cb, Fv, rr, zl, zr, vs);
        float sq = 0.f, sk = 0.f;
#pragma unroll
        for (int i = 0; i < 4; i++) {
            sq = fmaf(qs[i], qs[i], sq);
            sk = fmaf(ks[i], ks[i], sk);
        }
        float qi = rsq_(sum16(sq) + 1e-8f);
        float ki = rsq_(sum16(sk) + 1e-8f);
        uint2 av = *(const uint2*)(Fa + rr * LSTRIDE + cb);
        uint2 bv = *(const uint2*)(Fb + rr * LSTRIDE + cb);
        float af[4] = {lo2f(av.x), hi2f(av.x), lo2f(av.y), hi2f(av.y)};
        float bf[4] = {lo2f(bv.x), hi2f(bv.x), lo2f(bv.y), hi2f(bv.y)};
        float d2[4]; float sm = 0.f, sm2 = 0.f;
#pragma unroll
        for (int i = 0; i < 4; i++) {
            float delta = (qs[i] * qi) * (ks[i] * ki) * vs[i];
            d2[i] = fmaf(tanhf_(af[i]), delta, bf[i]);
            sm += d2[i];
            sm2 = fmaf(d2[i], d2[i], sm2);
        }
        sm = sum16(sm); sm2 = sum16(sm2);
        float mean = sm * (1.f / 64.f);
        float var  = fmaxf(fmaf(-mean, mean, sm2 * (1.f / 64.f)), 0.f);
        float inv  = rsq_(var + 1e-8f);
        const f32x4 pgv = *(const f32x4*)(post_g + cb);
        uint2 npk;
        npk.x = pk2((d2[0] - mean) * inv * pgv[0], (d2[1] - mean) * inv * pgv[1]);
        npk.y = pk2((d2[2] - mean) * inv * pgv[2], (d2[3] - mean) * inv * pgv[3]);
        *(uint2*)(Hs + rr * LSTRIDE + cb) = npk;   // Ns into Hs rows 1..32
    }
    __syncthreads();

    // ---- Stage D: dhat = Ns @ pw^T + pb (2 strips on waves 0,1) ------------
    if (wave < 2)
        mm32(wpack + 5 * 4096, pbf, Hs, Fq, 1, wave, lane);
    __syncthreads();

    // ---- Stage E: out = x + sigmoid(silu(dhat))*dhat -----------------------
    {
        const int rr = rgrp + 1;                // 1..32
        const int t = t0 + rgrp;
        uint2 dpk = *(const uint2*)(Fq + rr * LSTRIDE + cb);
        float dh[4] = {lo2f(dpk.x), hi2f(dpk.x), lo2f(dpk.y), hi2f(dpk.y)};
        const float* xrow = xg + ((size_t)b * T_LEN + t) * DD + cb;
        f32x4 xv = *(const f32x4*)(xrow);
        f32x4 ov;
#pragma unroll
        for (int i = 0; i < 4; i++) {
            float sl = dh[i] * sigmoidf_(dh[i]);
            ov[i] = xv[i] + sigmoidf_(sl) * dh[i];
        }
        *(f32x4*)(outg + ((size_t)b * T_LEN + t) * DD + cb) = ov;
    }
}

extern "C" void kernel_launch(void* const* d_in, const int* in_sizes, int n_in,
                              void* d_out, int out_size, void* d_ws, size_t ws_size,
                              hipStream_t stream) {
    const float* xg     = (const float*)d_in[0];
    const float* norm_g = (const float*)d_in[1];
    const float* qw  = (const float*)d_in[2];
    const float* qb  = (const float*)d_in[3];
    const float* kw  = (const float*)d_in[4];
    const float* kb  = (const float*)d_in[5];
    const float* vw  = (const float*)d_in[6];
    const float* vb  = (const float*)d_in[7];
    const float* qcw = (const float*)d_in[8];
    const float* qcb = (const float*)d_in[9];
    const float* kcw = (const float*)d_in[10];
    const float* kcb = (const float*)d_in[11];
    const float* vcw = (const float*)d_in[12];
    const float* vcb = (const float*)d_in[13];
    const float* aw  = (const float*)d_in[14];
    const float* ab  = (const float*)d_in[15];
    const float* bw  = (const float*)d_in[16];
    const float* bb  = (const float*)d_in[17];
    const float* pg  = (const float*)d_in[18];
    const float* pw  = (const float*)d_in[19];
    const float* pb  = (const float*)d_in[20];

    ushort_t* wpack = (ushort_t*)d_ws;

    hipLaunchKernelGGL(cvt_kernel, dim3(96), dim3(256), 0, stream,
                       qw, kw, vw, aw, bw, pw, wpack);

    const int B = in_sizes[0] / (T_LEN * DD);
    const int tiles_per_b = T_LEN / TBS;    // 128
    hipLaunchKernelGGL(gdn_kernel, dim3(B * tiles_per_b), dim3(512), 0, stream,
                       xg, norm_g, wpack, qcw, qcb, kcw, kcb, vcw, vcb,
                       qb, kb, vb, ab, bb, pb, pg,
                       (float*)d_out, tiles_per_b);
}